// Round 1
// baseline (355.805 us; speedup 1.0000x reference)
//
#include <hip/hip_runtime.h>
#include <hip/hip_bf16.h>

// TriangleMultiplication on MI355X (gfx950).
// Pipeline: k_prep (weights->bf16,T) ; k_proj<0> (leftT) ; k_proj<1> (rightTT) ;
//           k_tri (128x batched 512^3 bf16 MFMA GEMM) ; k_final (Wo + gate + residual + LN).
// ws layout: WlT|WrT|WgT|WoT (4*32KB) + leftT (64MB) + rightTT (64MB) + tri (64MB) = ~192.2MB

#define LSZ 512
#define NPOS (LSZ * LSZ)  // 262144 positions

typedef short s16;
typedef __attribute__((ext_vector_type(4))) short s16x4;
typedef __attribute__((ext_vector_type(8))) short s16x8;
typedef __attribute__((ext_vector_type(4))) float f32x4;

typedef const __attribute__((address_space(1))) unsigned int* gas1;
typedef __attribute__((address_space(3))) unsigned int* las3;

static __device__ __forceinline__ s16 f2bf(float f) {
    // round-to-nearest-even fp32 -> bf16 (finite values)
    unsigned int u = __builtin_bit_cast(unsigned int, f);
    u += 0x7FFFu + ((u >> 16) & 1u);
    return (s16)(u >> 16);
}

static __device__ __forceinline__ void gload_lds16(const void* g, void* l) {
    // 16B-per-lane async global->LDS; LDS dest must be wave-uniform base (+lane*16 in HW)
    __builtin_amdgcn_global_load_lds((gas1)g, (las3)l, 16, 0, 0);
}

// ---------------- K0: transpose weights to bf16 [out][in] ----------------
__global__ void k_prep(const float* __restrict__ Wl, const float* __restrict__ Wr,
                       const float* __restrict__ Wg, const float* __restrict__ Wo,
                       s16* __restrict__ WlT, s16* __restrict__ WrT,
                       s16* __restrict__ WgT, s16* __restrict__ WoT) {
    const float* src;
    s16* dst;
    switch (blockIdx.x) {
        case 0: src = Wl; dst = WlT; break;
        case 1: src = Wr; dst = WrT; break;
        case 2: src = Wg; dst = WgT; break;
        default: src = Wo; dst = WoT; break;
    }
    for (int e = threadIdx.x; e < 128 * 128; e += blockDim.x) {
        int o = e >> 7, i = e & 127;
        dst[e] = f2bf(src[i * 128 + o]);  // WT[o][i] = W[i][o]
    }
}

// ---------------- K1: projection GEMM, output transposed [h][pos] ----------------
// COLMODE=0: block b covers linear positions b*128.. (writes leftT[h][pos])
// COLMODE=1: block b covers a column strip (r=rb*128..+128, c fixed) -> rightTT[h][c][r]
template <int COLMODE>
__global__ __launch_bounds__(256) void k_proj(const float* __restrict__ pair,
                                              const s16* __restrict__ WT,
                                              const float* __restrict__ bias,
                                              s16* __restrict__ outT) {
    __shared__ __align__(16) s16 As[128 * 128];  // 32KB, XOR-swizzled rows (256B)
    const int t = threadIdx.x;
    const int b = blockIdx.x;
    const int c0 = b & 511, rb = b >> 9;  // used when COLMODE==1
    // ---- stage: 128 pos x 128 d fp32 -> bf16 LDS ----
    {
        const int p = t >> 1;
        const int dh = (t & 1) << 6;  // 0 or 64
        long gpos = COLMODE ? ((long)(rb * 128 + p) * 512 + c0) : ((long)b * 128 + p);
        const float* src = pair + gpos * 128 + dh;
        const int swz = (p & 7) << 4;
        char* lrow = (char*)As + p * 256;
#pragma unroll
        for (int g = 0; g < 8; ++g) {
            f32x4 v0 = *(const f32x4*)(src + g * 8);
            f32x4 v1 = *(const f32x4*)(src + g * 8 + 4);
            s16x8 pk;
            pk[0] = f2bf(v0[0]); pk[1] = f2bf(v0[1]); pk[2] = f2bf(v0[2]); pk[3] = f2bf(v0[3]);
            pk[4] = f2bf(v1[0]); pk[5] = f2bf(v1[1]); pk[6] = f2bf(v1[2]); pk[7] = f2bf(v1[3]);
            *(s16x8*)(lrow + ((dh * 2 + g * 16) ^ swz)) = pk;
        }
    }
    __syncthreads();
    // ---- 4 waves, each 64 pos x 64 h, K=128 ----
    const int w = t >> 6, l = t & 63;
    const int wr = (w >> 1) * 64, wc = (w & 1) * 64;
    const int lr = l & 15, lg = l >> 4;
    f32x4 acc[4][4];
#pragma unroll
    for (int mi = 0; mi < 4; ++mi)
#pragma unroll
        for (int ni = 0; ni < 4; ++ni) acc[mi][ni] = (f32x4){0.f, 0.f, 0.f, 0.f};
#pragma unroll
    for (int ks = 0; ks < 4; ++ks) {
        const int kk = ks * 32 + lg * 8;
        s16x8 af[4], bfv[4];
#pragma unroll
        for (int mi = 0; mi < 4; ++mi) {
            int row = wr + mi * 16 + lr;
            af[mi] = *(const s16x8*)((const char*)As + ((row * 256 + kk * 2) ^ ((row & 7) << 4)));
        }
#pragma unroll
        for (int ni = 0; ni < 4; ++ni) {
            int h = wc + ni * 16 + lr;
            bfv[ni] = *(const s16x8*)(WT + h * 128 + kk);  // WT is [h][d], L1-resident
        }
#pragma unroll
        for (int mi = 0; mi < 4; ++mi)
#pragma unroll
            for (int ni = 0; ni < 4; ++ni)
                acc[mi][ni] = __builtin_amdgcn_mfma_f32_16x16x32_bf16(af[mi], bfv[ni], acc[mi][ni], 0, 0, 0);
    }
    // ---- epilogue: +bias, bf16, store [h][pos] (4 consecutive pos -> 8B store) ----
#pragma unroll
    for (int ni = 0; ni < 4; ++ni) {
        const int h = wc + ni * 16 + lr;
        const float bv = bias[h];
        long base = (long)h * NPOS + (COLMODE ? ((long)c0 * 512 + rb * 128) : ((long)b * 128));
#pragma unroll
        for (int mi = 0; mi < 4; ++mi) {
            const int prow = wr + mi * 16 + lg * 4;
            s16x4 pk;
#pragma unroll
            for (int r = 0; r < 4; ++r) pk[r] = f2bf(acc[mi][ni][r] + bv);
            *(s16x4*)(outT + base + prow) = pk;
        }
    }
}

// ---------------- K2: triangle einsum = 128 batched 512^3 GEMMs ----------------
// C_h[i][j] = sum_k leftT[h][i][k] * rightTT[h][j][k]   (A row-major, B in B^T form)
__global__ __launch_bounds__(256) void k_tri(const s16* __restrict__ leftT,
                                             const s16* __restrict__ rightTT,
                                             s16* __restrict__ tri) {
    __shared__ __align__(16) s16 As[128 * 64];  // 16KB each, XOR-swizzled
    __shared__ __align__(16) s16 Bs[128 * 64];
    const int t = threadIdx.x;
    // XCD swizzle: all 16 tiles of one h-GEMM land on one XCD (2048 % 8 == 0, bijective)
    const int logical = ((blockIdx.x & 7) << 8) | (blockIdx.x >> 3);
    const int h = logical >> 4;
    const int ti = (logical >> 2) & 3, tj = logical & 3;
    const s16* Ap = leftT + (long)h * NPOS + ti * 128 * 512;
    const s16* Bp = rightTT + (long)h * NPOS + tj * 128 * 512;
    const int w = t >> 6, l = t & 63;
    const int wr = (w >> 1) * 64, wc = (w & 1) * 64;
    const int lr = l & 15, lg = l >> 4;
    const int srow = t >> 3;       // staging row within 32-row chunk
    const int skk = (t & 7) << 3;  // staging k offset (8 elems)
    f32x4 acc[4][4];
#pragma unroll
    for (int mi = 0; mi < 4; ++mi)
#pragma unroll
        for (int ni = 0; ni < 4; ++ni) acc[mi][ni] = (f32x4){0.f, 0.f, 0.f, 0.f};
    for (int kb = 0; kb < 512; kb += 64) {
        __syncthreads();  // LDS reuse guard
        // stage A,B tiles (128x64 bf16 each) via global_load_lds, source pre-swizzled
#pragma unroll
        for (int P = 0; P < 4; ++P) {
            int row = P * 32 + srow;
            int kks = skk ^ ((row & 7) << 3);  // inverse of read-side XOR (involution)
            unsigned loff = P * 4096 + w * 1024;
            gload_lds16(Ap + row * 512 + kb + kks, (char*)As + loff);
            gload_lds16(Bp + row * 512 + kb + kks, (char*)Bs + loff);
        }
        __syncthreads();
#pragma unroll
        for (int ks = 0; ks < 2; ++ks) {
            const int kk = ks * 32 + lg * 8;
            s16x8 af[4], bfv[4];
#pragma unroll
            for (int mi = 0; mi < 4; ++mi) {
                int row = wr + mi * 16 + lr;
                af[mi] = *(const s16x8*)((const char*)As + ((row * 128 + kk * 2) ^ ((row & 7) << 4)));
            }
#pragma unroll
            for (int ni = 0; ni < 4; ++ni) {
                int row = wc + ni * 16 + lr;
                bfv[ni] = *(const s16x8*)((const char*)Bs + ((row * 128 + kk * 2) ^ ((row & 7) << 4)));
            }
#pragma unroll
            for (int mi = 0; mi < 4; ++mi)
#pragma unroll
                for (int ni = 0; ni < 4; ++ni)
                    acc[mi][ni] = __builtin_amdgcn_mfma_f32_16x16x32_bf16(af[mi], bfv[ni], acc[mi][ni], 0, 0, 0);
        }
    }
    // epilogue: bf16 store to tri[h][i][j] (lanes 0-15 contiguous j)
#pragma unroll
    for (int mi = 0; mi < 4; ++mi) {
#pragma unroll
        for (int r = 0; r < 4; ++r) {
            int i = ti * 128 + wr + mi * 16 + lg * 4 + r;
            s16* dst = tri + (long)h * NPOS + (long)i * 512 + tj * 128 + wc;
#pragma unroll
            for (int ni = 0; ni < 4; ++ni) dst[ni * 16 + lr] = f2bf(acc[mi][ni][r]);
        }
    }
}

// ---------------- K3: out2 = tri@Wo+bo ; gate = sigmoid(pair@Wg+bg) ;
//                  y = LN(pair + gate*out2)*gamma + beta ----------------
__global__ __launch_bounds__(256) void k_final(const float* __restrict__ pair,
                                               const s16* __restrict__ tri,
                                               const s16* __restrict__ WgT,
                                               const s16* __restrict__ WoT,
                                               const float* __restrict__ bgv,
                                               const float* __restrict__ bov,
                                               const float* __restrict__ gam,
                                               const float* __restrict__ bet,
                                               float* __restrict__ out) {
    __shared__ __align__(16) s16 Ps[64 * 128];  // pair bf16, swizzled [pos][d]
    __shared__ __align__(16) s16 Ts[128 * 64];  // tri bf16, linear [h][pos_local]
    const int t = threadIdx.x;
    const long posBase = (long)blockIdx.x * 64;
    const int w = t >> 6;
    // stage pair tile (64 pos x 128 d) fp32 -> bf16
    {
        const int p = t >> 2;
        const int dq = (t & 3) << 5;
        const float* src = pair + (posBase + p) * 128 + dq;
        const int swz = (p & 7) << 4;
        char* lrow = (char*)Ps + p * 256;
#pragma unroll
        for (int g = 0; g < 4; ++g) {
            f32x4 v0 = *(const f32x4*)(src + g * 8);
            f32x4 v1 = *(const f32x4*)(src + g * 8 + 4);
            s16x8 pk;
            pk[0] = f2bf(v0[0]); pk[1] = f2bf(v0[1]); pk[2] = f2bf(v0[2]); pk[3] = f2bf(v0[3]);
            pk[4] = f2bf(v1[0]); pk[5] = f2bf(v1[1]); pk[6] = f2bf(v1[2]); pk[7] = f2bf(v1[3]);
            *(s16x8*)(lrow + ((dq * 2 + g * 16) ^ swz)) = pk;
        }
    }
    // stage tri tile (128 h x 64 pos) bf16, linear, async
    {
        const int srow = t >> 3;
        const int spl = (t & 7) << 3;
#pragma unroll
        for (int P = 0; P < 4; ++P) {
            int hh = P * 32 + srow;
            gload_lds16(tri + (long)hh * NPOS + posBase + spl, (char*)Ts + P * 4096 + w * 1024);
        }
    }
    __syncthreads();
    const int l = t & 63;
    const int lr = l & 15, lg = l >> 4;
    const int pw = w << 4;  // wave's 16-pos slice
    f32x4 accG[8], accO[8];
#pragma unroll
    for (int ni = 0; ni < 8; ++ni) {
        accG[ni] = (f32x4){0.f, 0.f, 0.f, 0.f};
        accO[ni] = (f32x4){0.f, 0.f, 0.f, 0.f};
    }
#pragma unroll
    for (int ks = 0; ks < 4; ++ks) {
        const int kk = ks * 32 + lg * 8;
        const int row = pw + lr;
        s16x8 ag = *(const s16x8*)((const char*)Ps + ((row * 256 + kk * 2) ^ ((row & 7) << 4)));
        s16x8 ao;  // transposed gather A[pos][h] from Ts[h][pos]
#pragma unroll
        for (int j = 0; j < 8; ++j) ao[j] = Ts[(kk + j) * 64 + pw + lr];
#pragma unroll
        for (int ni = 0; ni < 8; ++ni) {
            const int d = ni * 16 + lr;
            s16x8 bg8 = *(const s16x8*)(WgT + d * 128 + kk);
            s16x8 bo8 = *(const s16x8*)(WoT + d * 128 + kk);
            accG[ni] = __builtin_amdgcn_mfma_f32_16x16x32_bf16(ag, bg8, accG[ni], 0, 0, 0);
            accO[ni] = __builtin_amdgcn_mfma_f32_16x16x32_bf16(ao, bo8, accO[ni], 0, 0, 0);
        }
    }
    // fused epilogue: gate, residual, LayerNorm (row = 16 lanes x 8 frags)
    float xv[8][4];
#pragma unroll
    for (int ni = 0; ni < 8; ++ni) {
        const int d = ni * 16 + lr;
        const float bgs = bgv[d], bos = bov[d];
#pragma unroll
        for (int r = 0; r < 4; ++r) {
            long pos = posBase + pw + lg * 4 + r;
            float gl = accG[ni][r] + bgs;
            float gate = 1.f / (1.f + __expf(-gl));
            xv[ni][r] = pair[pos * 128 + d] + gate * (accO[ni][r] + bos);
        }
    }
#pragma unroll
    for (int r = 0; r < 4; ++r) {
        float s = 0.f;
#pragma unroll
        for (int ni = 0; ni < 8; ++ni) s += xv[ni][r];
        s += __shfl_xor(s, 1); s += __shfl_xor(s, 2);
        s += __shfl_xor(s, 4); s += __shfl_xor(s, 8);
        const float mu = s * 0.0078125f;
        float v = 0.f;
#pragma unroll
        for (int ni = 0; ni < 8; ++ni) { float dd = xv[ni][r] - mu; v += dd * dd; }
        v += __shfl_xor(v, 1); v += __shfl_xor(v, 2);
        v += __shfl_xor(v, 4); v += __shfl_xor(v, 8);
        const float rstd = rsqrtf(v * 0.0078125f + 1e-5f);
        const long pos = posBase + pw + lg * 4 + r;
#pragma unroll
        for (int ni = 0; ni < 8; ++ni) {
            const int d = ni * 16 + lr;
            out[pos * 128 + d] = (xv[ni][r] - mu) * rstd * gam[d] + bet[d];
        }
    }
}

extern "C" void kernel_launch(void* const* d_in, const int* in_sizes, int n_in,
                              void* d_out, int out_size, void* d_ws, size_t ws_size,
                              hipStream_t stream) {
    const float* pair = (const float*)d_in[0];
    const float* Wl   = (const float*)d_in[1];
    const float* bl   = (const float*)d_in[2];
    const float* Wr   = (const float*)d_in[3];
    const float* br   = (const float*)d_in[4];
    const float* Wo   = (const float*)d_in[5];
    const float* bo   = (const float*)d_in[6];
    const float* Wg   = (const float*)d_in[7];
    const float* bg   = (const float*)d_in[8];
    const float* gam  = (const float*)d_in[9];
    const float* bet  = (const float*)d_in[10];
    float* out = (float*)d_out;

    s16* WlT = (s16*)d_ws;
    s16* WrT = WlT + 128 * 128;
    s16* WgT = WrT + 128 * 128;
    s16* WoT = WgT + 128 * 128;
    s16* leftT   = WoT + 128 * 128;            // [128][NPOS]
    s16* rightTT = leftT + (long)128 * NPOS;   // [128][NPOS] (j-major, k fast)
    s16* tri     = rightTT + (long)128 * NPOS; // [128][NPOS]

    k_prep<<<4, 256, 0, stream>>>(Wl, Wr, Wg, Wo, WlT, WrT, WgT, WoT);
    k_proj<0><<<2048, 256, 0, stream>>>(pair, WlT, bl, leftT);
    k_proj<1><<<2048, 256, 0, stream>>>(pair, WrT, br, rightTT);
    k_tri<<<2048, 256, 0, stream>>>(leftT, rightTT, tri);
    k_final<<<4096, 256, 0, stream>>>(pair, tri, WgT, WoT, bg, bo, gam, bet, out);
}

// Round 2
// 354.876 us; speedup vs baseline: 1.0026x; 1.0026x over previous
//
#include <hip/hip_runtime.h>
#include <hip/hip_bf16.h>

// TriangleMultiplication on MI355X (gfx950).
// Pipeline: k_prep (weights->bf16,T) ; k_proj<0> (leftT) ; k_proj<1> (rightTT) ;
//           k_tri (128x batched 512^3 bf16 MFMA GEMM) ; k_final (Wo + gate + residual + LN).
// ws layout: WlT|WrT|WgT|WoT (4*32KB) + leftT (64MB) + rightTT (64MB) + tri (64MB) = ~192.2MB

#define LSZ 512
#define NPOS (LSZ * LSZ)  // 262144 positions

typedef short s16;
typedef __attribute__((ext_vector_type(4))) short s16x4;
typedef __attribute__((ext_vector_type(8))) short s16x8;
typedef __attribute__((ext_vector_type(4))) float f32x4;

typedef const __attribute__((address_space(1))) unsigned int* gas1;
typedef __attribute__((address_space(3))) unsigned int* las3;

static __device__ __forceinline__ s16 f2bf(float f) {
    // round-to-nearest-even fp32 -> bf16 (finite values)
    unsigned int u = __builtin_bit_cast(unsigned int, f);
    u += 0x7FFFu + ((u >> 16) & 1u);
    return (s16)(u >> 16);
}

static __device__ __forceinline__ void gload_lds16(const void* g, void* l) {
    // 16B-per-lane async global->LDS; LDS dest must be wave-uniform base (+lane*16 in HW)
    __builtin_amdgcn_global_load_lds((gas1)g, (las3)l, 16, 0, 0);
}

// ---------------- K0: transpose weights to bf16 [out][in] ----------------
__global__ void k_prep(const float* __restrict__ Wl, const float* __restrict__ Wr,
                       const float* __restrict__ Wg, const float* __restrict__ Wo,
                       s16* __restrict__ WlT, s16* __restrict__ WrT,
                       s16* __restrict__ WgT, s16* __restrict__ WoT) {
    const float* src;
    s16* dst;
    switch (blockIdx.x) {
        case 0: src = Wl; dst = WlT; break;
        case 1: src = Wr; dst = WrT; break;
        case 2: src = Wg; dst = WgT; break;
        default: src = Wo; dst = WoT; break;
    }
    for (int e = threadIdx.x; e < 128 * 128; e += blockDim.x) {
        int o = e >> 7, i = e & 127;
        dst[e] = f2bf(src[i * 128 + o]);  // WT[o][i] = W[i][o]
    }
}

// ---------------- K1: projection GEMM, output transposed [h][pos] ----------------
// COLMODE=0: block b covers linear positions b*128.. (writes leftT[h][pos])
// COLMODE=1: block b covers a column strip (r=rb*128..+128, c fixed) -> rightTT[h][c][r]
template <int COLMODE>
__global__ __launch_bounds__(256) void k_proj(const float* __restrict__ pair,
                                              const s16* __restrict__ WT,
                                              const float* __restrict__ bias,
                                              s16* __restrict__ outT) {
    __shared__ __align__(16) s16 As[128 * 128];  // 32KB, XOR-swizzled rows (256B)
    const int t = threadIdx.x;
    const int b = blockIdx.x;
    const int c0 = b & 511, rb = b >> 9;  // used when COLMODE==1
    // ---- stage: 128 pos x 128 d fp32 -> bf16 LDS ----
    {
        const int p = t >> 1;
        const int dh = (t & 1) << 6;  // 0 or 64
        long gpos = COLMODE ? ((long)(rb * 128 + p) * 512 + c0) : ((long)b * 128 + p);
        const float* src = pair + gpos * 128 + dh;
        const int swz = (p & 7) << 4;
        char* lrow = (char*)As + p * 256;
#pragma unroll
        for (int g = 0; g < 8; ++g) {
            f32x4 v0 = *(const f32x4*)(src + g * 8);
            f32x4 v1 = *(const f32x4*)(src + g * 8 + 4);
            s16x8 pk;
            pk[0] = f2bf(v0[0]); pk[1] = f2bf(v0[1]); pk[2] = f2bf(v0[2]); pk[3] = f2bf(v0[3]);
            pk[4] = f2bf(v1[0]); pk[5] = f2bf(v1[1]); pk[6] = f2bf(v1[2]); pk[7] = f2bf(v1[3]);
            *(s16x8*)(lrow + ((dh * 2 + g * 16) ^ swz)) = pk;
        }
    }
    __syncthreads();
    // ---- 4 waves, each 64 pos x 64 h, K=128 ----
    const int w = t >> 6, l = t & 63;
    const int wr = (w >> 1) * 64, wc = (w & 1) * 64;
    const int lr = l & 15, lg = l >> 4;
    f32x4 acc[4][4];
#pragma unroll
    for (int mi = 0; mi < 4; ++mi)
#pragma unroll
        for (int ni = 0; ni < 4; ++ni) acc[mi][ni] = (f32x4){0.f, 0.f, 0.f, 0.f};
#pragma unroll
    for (int ks = 0; ks < 4; ++ks) {
        const int kk = ks * 32 + lg * 8;
        s16x8 af[4], bfv[4];
#pragma unroll
        for (int mi = 0; mi < 4; ++mi) {
            int row = wr + mi * 16 + lr;
            af[mi] = *(const s16x8*)((const char*)As + ((row * 256 + kk * 2) ^ ((row & 7) << 4)));
        }
#pragma unroll
        for (int ni = 0; ni < 4; ++ni) {
            int h = wc + ni * 16 + lr;
            bfv[ni] = *(const s16x8*)(WT + h * 128 + kk);  // WT is [h][d], L1-resident
        }
#pragma unroll
        for (int mi = 0; mi < 4; ++mi)
#pragma unroll
            for (int ni = 0; ni < 4; ++ni)
                acc[mi][ni] = __builtin_amdgcn_mfma_f32_16x16x32_bf16(af[mi], bfv[ni], acc[mi][ni], 0, 0, 0);
    }
    // ---- epilogue: +bias, bf16, store [h][pos] (4 consecutive pos -> 8B store) ----
#pragma unroll
    for (int ni = 0; ni < 4; ++ni) {
        const int h = wc + ni * 16 + lr;
        const float bv = bias[h];
        long base = (long)h * NPOS + (COLMODE ? ((long)c0 * 512 + rb * 128) : ((long)b * 128));
#pragma unroll
        for (int mi = 0; mi < 4; ++mi) {
            const int prow = wr + mi * 16 + lg * 4;
            s16x4 pk;
#pragma unroll
            for (int r = 0; r < 4; ++r) pk[r] = f2bf(acc[mi][ni][r] + bv);
            *(s16x4*)(outT + base + prow) = pk;
        }
    }
}

// ---------------- K2: triangle einsum = 128 batched 512^3 GEMMs ----------------
// C_h[i][j] = sum_k leftT[h][i][k] * rightTT[h][j][k]   (A row-major, B in B^T form)
__global__ __launch_bounds__(256) void k_tri(const s16* __restrict__ leftT,
                                             const s16* __restrict__ rightTT,
                                             s16* __restrict__ tri) {
    __shared__ __align__(16) s16 As[128 * 64];  // 16KB each, XOR-swizzled
    __shared__ __align__(16) s16 Bs[128 * 64];
    const int t = threadIdx.x;
    // XCD swizzle: all 16 tiles of one h-GEMM land on one XCD (2048 % 8 == 0, bijective)
    const int logical = ((blockIdx.x & 7) << 8) | (blockIdx.x >> 3);
    const int h = logical >> 4;
    const int ti = (logical >> 2) & 3, tj = logical & 3;
    const s16* Ap = leftT + (long)h * NPOS + ti * 128 * 512;
    const s16* Bp = rightTT + (long)h * NPOS + tj * 128 * 512;
    const int w = t >> 6, l = t & 63;
    const int wr = (w >> 1) * 64, wc = (w & 1) * 64;
    const int lr = l & 15, lg = l >> 4;
    const int srow = t >> 3;       // staging row within 32-row chunk
    const int skk = (t & 7) << 3;  // staging k offset (8 elems)
    f32x4 acc[4][4];
#pragma unroll
    for (int mi = 0; mi < 4; ++mi)
#pragma unroll
        for (int ni = 0; ni < 4; ++ni) acc[mi][ni] = (f32x4){0.f, 0.f, 0.f, 0.f};
    for (int kb = 0; kb < 512; kb += 64) {
        __syncthreads();  // LDS reuse guard
        // stage A,B tiles (128x64 bf16 each) via global_load_lds, source pre-swizzled
#pragma unroll
        for (int P = 0; P < 4; ++P) {
            int row = P * 32 + srow;
            int kks = skk ^ ((row & 7) << 3);  // inverse of read-side XOR (involution)
            unsigned loff = P * 4096 + w * 1024;
            gload_lds16(Ap + row * 512 + kb + kks, (char*)As + loff);
            gload_lds16(Bp + row * 512 + kb + kks, (char*)Bs + loff);
        }
        __syncthreads();
#pragma unroll
        for (int ks = 0; ks < 2; ++ks) {
            const int kk = ks * 32 + lg * 8;
            s16x8 af[4], bfv[4];
#pragma unroll
            for (int mi = 0; mi < 4; ++mi) {
                int row = wr + mi * 16 + lr;
                af[mi] = *(const s16x8*)((const char*)As + ((row * 128 + kk * 2) ^ ((row & 7) << 4)));
            }
#pragma unroll
            for (int ni = 0; ni < 4; ++ni) {
                int row = wc + ni * 16 + lr;
                bfv[ni] = *(const s16x8*)((const char*)Bs + ((row * 128 + kk * 2) ^ ((row & 7) << 4)));
            }
#pragma unroll
            for (int mi = 0; mi < 4; ++mi)
#pragma unroll
                for (int ni = 0; ni < 4; ++ni)
                    acc[mi][ni] = __builtin_amdgcn_mfma_f32_16x16x32_bf16(af[mi], bfv[ni], acc[mi][ni], 0, 0, 0);
        }
    }
    // epilogue: bf16 store to tri[h][i][j] (lanes 0-15 contiguous j)
#pragma unroll
    for (int mi = 0; mi < 4; ++mi) {
#pragma unroll
        for (int r = 0; r < 4; ++r) {
            int i = ti * 128 + wr + mi * 16 + lg * 4 + r;
            s16* dst = tri + (long)h * NPOS + (long)i * 512 + tj * 128 + wc;
#pragma unroll
            for (int ni = 0; ni < 4; ++ni) dst[ni * 16 + lr] = f2bf(acc[mi][ni][r]);
        }
    }
}

// ---------------- K3: out2 = tri@Wo+bo ; gate = sigmoid(pair@Wg+bg) ;
//                  y = LN(pair + gate*out2)*gamma + beta ----------------
// Pf layout: fp32, row stride 132 words; 16B units rotated (5-bit rotl2) so that
// staging writes, fragment reads, scalar updates, and row-major LN reads all
// spread evenly across the 32 LDS banks.
static __device__ __forceinline__ int pfoff(int row, int col) {
    int u = col >> 2;                          // 16B unit 0..31
    int u2 = ((u & 7) << 2) | (u >> 3);        // bijective 5-bit rotate
    return row * 132 + (u2 << 2) + (col & 3);  // word index
}

__global__ __launch_bounds__(256) void k_final(const float* __restrict__ pair,
                                               const s16* __restrict__ tri,
                                               const s16* __restrict__ WgT,
                                               const s16* __restrict__ WoT,
                                               const float* __restrict__ bgv,
                                               const float* __restrict__ bov,
                                               const float* __restrict__ gam,
                                               const float* __restrict__ bet,
                                               float* __restrict__ out) {
    __shared__ __align__(16) float Pf[64 * 132];  // 33 KB fp32 pair, then in-place x
    __shared__ __align__(16) s16 Ts[128 * 64];    // 16 KB tri bf16, linear [h][pos_local]
    const int t = threadIdx.x;
    const long posBase = (long)blockIdx.x * 64;
    const int w = t >> 6;
    // ---- stage tri tile (128 h x 64 pos) bf16, linear, async ----
    {
        const int srow = t >> 3;
        const int spl = (t & 7) << 3;
#pragma unroll
        for (int P = 0; P < 4; ++P) {
            int hh = P * 32 + srow;
            gload_lds16(tri + (long)hh * NPOS + posBase + spl, (char*)Ts + P * 4096 + w * 1024);
        }
    }
    // ---- stage pair tile (64 pos x 128 d) fp32, coalesced f32x4 ----
    {
        const int p = t >> 2, q = t & 3;
        const float* src = pair + (posBase + p) * 128;
#pragma unroll
        for (int g = 0; g < 8; ++g) {
            const int col = g * 16 + q * 4;
            *(f32x4*)&Pf[pfoff(p, col)] = *(const f32x4*)(src + col);
        }
    }
    __syncthreads();  // Ts is consumed cross-wave; Pf rows are wave-private
    const int l = t & 63;
    const int lr = l & 15, lg = l >> 4;
    const int pw = w << 4;  // wave's 16-pos slice
    const int arow = pw + lr;
    f32x4 accG[8], accO[8];
#pragma unroll
    for (int ni = 0; ni < 8; ++ni) {
        accG[ni] = (f32x4){0.f, 0.f, 0.f, 0.f};
        accO[ni] = (f32x4){0.f, 0.f, 0.f, 0.f};
    }
#pragma unroll
    for (int ks = 0; ks < 4; ++ks) {
        const int kk = ks * 32 + lg * 8;
        f32x4 a0 = *(const f32x4*)&Pf[pfoff(arow, kk)];
        f32x4 a1 = *(const f32x4*)&Pf[pfoff(arow, kk + 4)];
        s16x8 ag;
        ag[0] = f2bf(a0[0]); ag[1] = f2bf(a0[1]); ag[2] = f2bf(a0[2]); ag[3] = f2bf(a0[3]);
        ag[4] = f2bf(a1[0]); ag[5] = f2bf(a1[1]); ag[6] = f2bf(a1[2]); ag[7] = f2bf(a1[3]);
        s16x8 ao;  // transposed gather A[pos][h] from Ts[h][pos]
#pragma unroll
        for (int j = 0; j < 8; ++j) ao[j] = Ts[(kk + j) * 64 + pw + lr];
#pragma unroll
        for (int ni = 0; ni < 8; ++ni) {
            const int d = ni * 16 + lr;
            s16x8 bg8 = *(const s16x8*)(WgT + d * 128 + kk);
            s16x8 bo8 = *(const s16x8*)(WoT + d * 128 + kk);
            accG[ni] = __builtin_amdgcn_mfma_f32_16x16x32_bf16(ag, bg8, accG[ni], 0, 0, 0);
            accO[ni] = __builtin_amdgcn_mfma_f32_16x16x32_bf16(ao, bo8, accO[ni], 0, 0, 0);
        }
    }
    // ---- P3: gate, residual; x written back in place into Pf (same lane slots) ----
#pragma unroll
    for (int ni = 0; ni < 8; ++ni) {
        const int d = ni * 16 + lr;
        const float bgs = bgv[d], bos = bov[d];
#pragma unroll
        for (int r = 0; r < 4; ++r) {
            const int posl = pw + lg * 4 + r;
            const int off = pfoff(posl, d);
            const float pv = Pf[off];
            const float gl = accG[ni][r] + bgs;
            const float gate = 1.f / (1.f + __expf(-gl));
            Pf[off] = pv + gate * (accO[ni][r] + bos);
        }
    }
    // ---- P4: LayerNorm + coalesced store. Thread t owns row t>>2 (same wave as
    // the lanes that wrote it in P3 -> wave-internal LDS ordering suffices). ----
    {
        const int p = t >> 2, q = t & 3;
        f32x4 vv[8];
        float s = 0.f;
#pragma unroll
        for (int g = 0; g < 8; ++g) {
            vv[g] = *(const f32x4*)&Pf[pfoff(p, g * 16 + q * 4)];
            s += vv[g][0] + vv[g][1] + vv[g][2] + vv[g][3];
        }
        s += __shfl_xor(s, 1);
        s += __shfl_xor(s, 2);
        const float mu = s * 0.0078125f;
        float v = 0.f;
#pragma unroll
        for (int g = 0; g < 8; ++g)
#pragma unroll
            for (int j = 0; j < 4; ++j) {
                float dd = vv[g][j] - mu;
                v += dd * dd;
            }
        v += __shfl_xor(v, 1);
        v += __shfl_xor(v, 2);
        const float rstd = rsqrtf(v * 0.0078125f + 1e-5f);
        float* dst = out + (posBase + p) * 128;
#pragma unroll
        for (int g = 0; g < 8; ++g) {
            const int d0 = g * 16 + q * 4;
            f32x4 gm = *(const f32x4*)(gam + d0);
            f32x4 bt = *(const f32x4*)(bet + d0);
            f32x4 o;
#pragma unroll
            for (int j = 0; j < 4; ++j) o[j] = (vv[g][j] - mu) * rstd * gm[j] + bt[j];
            *(f32x4*)(dst + d0) = o;
        }
    }
}

extern "C" void kernel_launch(void* const* d_in, const int* in_sizes, int n_in,
                              void* d_out, int out_size, void* d_ws, size_t ws_size,
                              hipStream_t stream) {
    const float* pair = (const float*)d_in[0];
    const float* Wl   = (const float*)d_in[1];
    const float* bl   = (const float*)d_in[2];
    const float* Wr   = (const float*)d_in[3];
    const float* br   = (const float*)d_in[4];
    const float* Wo   = (const float*)d_in[5];
    const float* bo   = (const float*)d_in[6];
    const float* Wg   = (const float*)d_in[7];
    const float* bg   = (const float*)d_in[8];
    const float* gam  = (const float*)d_in[9];
    const float* bet  = (const float*)d_in[10];
    float* out = (float*)d_out;

    s16* WlT = (s16*)d_ws;
    s16* WrT = WlT + 128 * 128;
    s16* WgT = WrT + 128 * 128;
    s16* WoT = WgT + 128 * 128;
    s16* leftT   = WoT + 128 * 128;            // [128][NPOS]
    s16* rightTT = leftT + (long)128 * NPOS;   // [128][NPOS] (j-major, k fast)
    s16* tri     = rightTT + (long)128 * NPOS; // [128][NPOS]

    k_prep<<<4, 256, 0, stream>>>(Wl, Wr, Wg, Wo, WlT, WrT, WgT, WoT);
    k_proj<0><<<2048, 256, 0, stream>>>(pair, WlT, bl, leftT);
    k_proj<1><<<2048, 256, 0, stream>>>(pair, WrT, br, rightTT);
    k_tri<<<2048, 256, 0, stream>>>(leftT, rightTT, tri);
    k_final<<<4096, 256, 0, stream>>>(pair, tri, WgT, WoT, bg, bo, gam, bet, out);
}